// Round 12
// baseline (231.842 us; speedup 1.0000x reference)
//
#include <hip/hip_runtime.h>
#include <hip/hip_fp16.h>
#include <math.h>

// ---------------------------------------------------------------------------
// GCNSim: 2-layer GCN. Bucket sort -> per-node CSR -> per-node register gather
// (32 lanes = 32 features per node, no LDS atomics).
// hw1h = fp16[(x@w1)*dis] rows of 64B; srcs[] = per-node-grouped neighbor ids.
// hw1s v4: thread=(row,khalf); xs row-major + ds_read_b128 (64 FMA per LDS
// read); w1 via SGPR s_load. scatterC: LDS value-scatter, coalesced out.
// Layer-2 aggregation computed only for the 4096 selected nodes.
// ---------------------------------------------------------------------------

#define NPB 64
#define NB_PAD 2048
#define BATCH 8192
#define NSCAP 12288

__global__ void zero_kernel(int* __restrict__ p, int c) {
    int i = blockIdx.x * 256 + threadIdx.x;
    if (i < c) p[i] = 0;
}

// ---- Pass A: per-bucket edge histogram (LDS-aggregated)
__global__ __launch_bounds__(256) void histA_kernel(const int* __restrict__ ei,
                                                    int* __restrict__ bhist, int nE, int nb) {
    __shared__ int h[NB_PAD];
    int tid = threadIdx.x;
    for (int t = tid; t < nb; t += 256) h[t] = 0;
    __syncthreads();
    int base = blockIdx.x * 4096;
    for (int t = tid; t < 4096; t += 256) {
        int e = base + t;
        if (e < nE) atomicAdd(&h[ei[nE + e] >> 6], 1);
    }
    __syncthreads();
    for (int t = tid; t < nb; t += 256) { int c = h[t]; if (c) atomicAdd(&bhist[t], c); }
}

// ---- Pass B: exclusive scan of bucket counts -> boffs[nb+1], gcur copy
__global__ __launch_bounds__(256) void scanB_kernel(const int* __restrict__ bhist,
                                                    int* __restrict__ boffs,
                                                    int* __restrict__ gcur, int nb) {
    int t = threadIdx.x;
    int v[8], s = 0;
    #pragma unroll
    for (int i = 0; i < 8; ++i) { int c = t * 8 + i; v[i] = (c < nb) ? bhist[c] : 0; s += v[i]; }
    int lane = t & 63, wid = t >> 6;
    int incl = s;
    for (int d = 1; d < 64; d <<= 1) { int u = __shfl_up(incl, (unsigned)d, 64); if (lane >= d) incl += u; }
    __shared__ int ws[4];
    if (lane == 63) ws[wid] = incl;
    __syncthreads();
    int add = 0;
    for (int w = 0; w < wid; ++w) add += ws[w];
    incl += add;
    int excl = incl - s;
    #pragma unroll
    for (int i = 0; i < 8; ++i) {
        int c = t * 8 + i;
        if (c < nb) { boffs[c] = excl; gcur[c] = excl; }
        excl += v[i];
    }
    if (t == 0) boffs[nb] = ws[0] + ws[1] + ws[2] + ws[3];
}

// ---- Pass C: value-scatter of packed keys into bucket regions.
__global__ __launch_bounds__(256) void scatterC_kernel(const int* __restrict__ ei,
                                                       int* __restrict__ gcur,
                                                       int* __restrict__ keys, int nE, int nb) {
    __shared__ int kbuf[BATCH];              // 32 KB
    __shared__ unsigned short kbk[BATCH];    // 16 KB
    __shared__ int lstart[NB_PAD];           // 8 KB
    __shared__ int cursor[NB_PAD];           // 8 KB
    __shared__ int gbase[NB_PAD];            // 8 KB
    __shared__ int ws2[4];
    int tid = threadIdx.x;
    int base = blockIdx.x * BATCH;
    int cnt = nE - base; if (cnt > BATCH) cnt = BATCH;
    for (int t = tid; t < nb; t += 256) lstart[t] = 0;
    __syncthreads();
    for (int t = tid; t < cnt; t += 256)
        atomicAdd(&lstart[ei[nE + base + t] >> 6], 1);
    __syncthreads();
    {
        int v[8], s = 0;
        #pragma unroll
        for (int i = 0; i < 8; ++i) { int c = tid * 8 + i; v[i] = (c < nb) ? lstart[c] : 0; s += v[i]; }
        int lane = tid & 63, wid = tid >> 6;
        int incl = s;
        for (int d = 1; d < 64; d <<= 1) { int u = __shfl_up(incl, (unsigned)d, 64); if (lane >= d) incl += u; }
        if (lane == 63) ws2[wid] = incl;
        __syncthreads();
        int add = 0;
        for (int w = 0; w < wid; ++w) add += ws2[w];
        incl += add;
        int excl = incl - s;
        #pragma unroll
        for (int i = 0; i < 8; ++i) {
            int c = tid * 8 + i;
            if (c < nb) { lstart[c] = excl; cursor[c] = excl; }
            excl += v[i];
        }
    }
    __syncthreads();
    for (int t = tid; t < nb; t += 256) {
        int e = (t == nb - 1) ? cnt : lstart[t + 1];
        int c = e - lstart[t];
        gbase[t] = c ? atomicAdd(&gcur[t], c) : 0;
    }
    for (int t = tid; t < cnt; t += 256) {
        int d = ei[nE + base + t];
        int s = ei[base + t];
        int b = d >> 6;
        int pos = atomicAdd(&cursor[b], 1);
        kbuf[pos] = s | ((d & 63) << 17);
        kbk[pos] = (unsigned short)b;
    }
    __syncthreads();
    for (int j = tid; j < cnt; j += 256) {
        int b = kbk[j];
        keys[gbase[b] + (j - lstart[b])] = kbuf[j];
    }
}

// ---- nodesort: bucket -> per-node CSR (in-place via LDS), noffs, dis
__global__ __launch_bounds__(256) void nodesort_kernel(int* __restrict__ keys,
                                                       const int* __restrict__ boffs,
                                                       int* __restrict__ noffs,
                                                       float* __restrict__ dis,
                                                       int n, int nbuck) {
    __shared__ int kb[NSCAP];     // 48 KB
    __shared__ int cnt[NPB], cur[NPB];
    int tid = threadIdx.x, b = blockIdx.x;
    int off = boffs[b], end = boffs[b + 1];
    int m = end - off; if (m > NSCAP) m = NSCAP;
    if (tid < NPB) cnt[tid] = 0;
    __syncthreads();
    for (int t = tid; t < m; t += 256) {
        int k = keys[off + t];
        kb[t] = k;
        atomicAdd(&cnt[k >> 17], 1);
    }
    __syncthreads();
    if (tid < NPB) {
        int v = cnt[tid];
        int incl = v;
        for (int d = 1; d < 64; d <<= 1) { int u = __shfl_up(incl, (unsigned)d, 64); if (tid >= d) incl += u; }
        int excl = incl - v;
        cur[tid] = excl;
        int node = b * NPB + tid;
        if (node < n) {
            noffs[node] = off + excl;
            dis[node] = rsqrtf((float)(v + 1));
        }
    }
    __syncthreads();
    for (int t = tid; t < m; t += 256) {
        int k = kb[t];
        int pos = atomicAdd(&cur[k >> 17], 1);
        keys[off + pos] = k & 0x1FFFF;
    }
    if (b == nbuck - 1 && tid == 0) noffs[n] = end;
}

// ---- hw1h = fp16[(x @ w1) * dis]: thread = (row, khalf).
// xs row-major [128][68] (16B-aligned rows); per 4-c group one ds_read_b128
// feeds 64 FMAs; w1 rows via wave-uniform s_load. K chunked x64.
__global__ __launch_bounds__(256) void hw1s_kernel(const float* __restrict__ x,
                                                   const float* __restrict__ w1,
                                                   const float* __restrict__ dis,
                                                   __half* __restrict__ hw1h, int n) {
    __shared__ float xs[128 * 68];   // 34.8 KB
    int tid = threadIdx.x;
    int row0 = blockIdx.x * 128;
    int r = tid & 127;
    int khs = __builtin_amdgcn_readfirstlane((tid >> 7) * 16);  // wave-uniform k-half
    float acc[16];
    #pragma unroll
    for (int k = 0; k < 16; ++k) acc[k] = 0.f;

    for (int ch = 0; ch < 4; ++ch) {
        int cc0 = ch * 64;
        __syncthreads();   // previous chunk's compute done
        #pragma unroll
        for (int i = 0; i < 8; ++i) {
            int gid = i * 256 + tid;
            int rr = gid >> 4, c4 = (gid & 15) << 2;
            int row = row0 + rr;
            float4 v = (row < n) ? *(const float4*)&x[(size_t)row * 256 + cc0 + c4]
                                 : make_float4(0.f, 0.f, 0.f, 0.f);
            *(float4*)&xs[rr * 68 + c4] = v;
        }
        __syncthreads();
        #pragma unroll 4
        for (int cg = 0; cg < 16; ++cg) {
            float4 xv = *(float4*)&xs[r * 68 + cg * 4];
            const float* wr = &w1[(size_t)(cc0 + cg * 4) * 32 + khs];   // uniform -> s_load
            #pragma unroll
            for (int k = 0; k < 16; ++k) acc[k] = fmaf(xv.x, wr[k], acc[k]);
            #pragma unroll
            for (int k = 0; k < 16; ++k) acc[k] = fmaf(xv.y, wr[32 + k], acc[k]);
            #pragma unroll
            for (int k = 0; k < 16; ++k) acc[k] = fmaf(xv.z, wr[64 + k], acc[k]);
            #pragma unroll
            for (int k = 0; k < 16; ++k) acc[k] = fmaf(xv.w, wr[96 + k], acc[k]);
        }
    }
    int row = row0 + r;
    if (row < n) {
        float dn = dis[row];
        __half2 h[8];
        #pragma unroll
        for (int k = 0; k < 8; ++k)
            h[k] = __floats2half2_rn(acc[2 * k] * dn, acc[2 * k + 1] * dn);
        float4* dst = (float4*)&hw1h[(size_t)row * 32 + khs];
        dst[0] = *(float4*)&h[0];
        dst[1] = *(float4*)&h[4];
    }
}

// ---- gatherG1: per-node register gather (32 lanes = 32 features), ReLU -> h1h
__global__ __launch_bounds__(256) void gatherG1_kernel(const __half* __restrict__ hw1h,
                                                       const float* __restrict__ dis,
                                                       const int* __restrict__ srcs,
                                                       const int* __restrict__ noffs,
                                                       const float* __restrict__ b1,
                                                       __half* __restrict__ h1h, int n) {
    int tid = threadIdx.x;
    int g = tid >> 5, k = tid & 31;
    int node = blockIdx.x * 8 + g;
    if (node >= n) return;
    int off = noffs[node], end = noffs[node + 1];
    float acc = 0.f;
    int e = off;
    for (; e + 8 <= end; e += 8) {
        int s0 = srcs[e],     s1 = srcs[e + 1], s2 = srcs[e + 2], s3 = srcs[e + 3];
        int s4 = srcs[e + 4], s5 = srcs[e + 5], s6 = srcs[e + 6], s7 = srcs[e + 7];
        float v0 = __half2float(hw1h[(size_t)s0 * 32 + k]);
        float v1 = __half2float(hw1h[(size_t)s1 * 32 + k]);
        float v2 = __half2float(hw1h[(size_t)s2 * 32 + k]);
        float v3 = __half2float(hw1h[(size_t)s3 * 32 + k]);
        float v4 = __half2float(hw1h[(size_t)s4 * 32 + k]);
        float v5 = __half2float(hw1h[(size_t)s5 * 32 + k]);
        float v6 = __half2float(hw1h[(size_t)s6 * 32 + k]);
        float v7 = __half2float(hw1h[(size_t)s7 * 32 + k]);
        acc += ((v0 + v1) + (v2 + v3)) + ((v4 + v5) + (v6 + v7));
    }
    for (; e < end; ++e)
        acc += __half2float(hw1h[(size_t)srcs[e] * 32 + k]);
    float dn = dis[node];
    float self = __half2float(hw1h[(size_t)node * 32 + k]);
    float h = fmaxf(dn * (acc + self) + b1[k], 0.f);
    h1h[(size_t)node * 32 + k] = __float2half(h);
}

// ---- gemm2: hw2s = (h1 @ w2) * dis   [N,32]x[32,16] -> [N,16] f32
__global__ __launch_bounds__(256) void gemm2_kernel(const __half* __restrict__ h1h,
                                                    const float* __restrict__ w2,
                                                    const float* __restrict__ dis,
                                                    float* __restrict__ hw2s, int n) {
    __shared__ float w2s[512];
    __shared__ float h1s[16][33];
    int tid = threadIdx.x;
    for (int t = tid; t < 512; t += 256) w2s[t] = w2[t];
    int node0 = blockIdx.x * 16;
    for (int t = tid; t < 512; t += 256) {
        int r = t >> 5, c = t & 31;
        int nd = node0 + r;
        h1s[r][c] = (nd < n) ? __half2float(h1h[(size_t)nd * 32 + c]) : 0.f;
    }
    __syncthreads();
    int r = tid >> 4, j = tid & 15;
    int nd = node0 + r;
    if (nd < n) {
        float a = 0.f;
        #pragma unroll
        for (int c = 0; c < 32; ++c) a += h1s[r][c] * w2s[c * 16 + j];
        hw2s[(size_t)nd * 16 + j] = a * dis[nd];
    }
}

// ---- gatherG2: layer-2 aggregation for SELECTED nodes only (16 lanes/node)
__global__ __launch_bounds__(256) void gatherG2_kernel(const float* __restrict__ hw2s,
                                                       const float* __restrict__ dis,
                                                       const int* __restrict__ srcs,
                                                       const int* __restrict__ noffs,
                                                       const int* __restrict__ nodes,
                                                       const float* __restrict__ b2,
                                                       float* __restrict__ h2, int nsel, int n) {
    int tid = threadIdx.x;
    int slot = tid >> 4, j = tid & 15;
    int i = blockIdx.x * 16 + slot;
    if (i >= nsel) return;
    int node = nodes[i];
    int off = noffs[node], end = noffs[node + 1];
    float acc = 0.f;
    int e = off;
    for (; e + 4 <= end; e += 4) {
        int s0 = srcs[e], s1 = srcs[e + 1], s2 = srcs[e + 2], s3 = srcs[e + 3];
        float v0 = hw2s[(size_t)s0 * 16 + j];
        float v1 = hw2s[(size_t)s1 * 16 + j];
        float v2 = hw2s[(size_t)s2 * 16 + j];
        float v3 = hw2s[(size_t)s3 * 16 + j];
        acc += (v0 + v1) + (v2 + v3);
    }
    for (; e < end; ++e) acc += hw2s[(size_t)srcs[e] * 16 + j];
    h2[(size_t)node * 16 + j] = dis[node] * (acc + hw2s[(size_t)node * 16 + j]) + b2[j];
}

// ---- pairwise concat + MoE1 + MoE2 + log_softmax
__global__ __launch_bounds__(256) void pair_moe_kernel(const float* __restrict__ h2,
                                                       const int* __restrict__ nodes,
                                                       const float* __restrict__ gate1_w,
                                                       const float* __restrict__ e1_w,
                                                       const float* __restrict__ e1_b,
                                                       const float* __restrict__ gate2_w,
                                                       const float* __restrict__ e2_w,
                                                       const float* __restrict__ e2_b,
                                                       float* __restrict__ out1,
                                                       float* __restrict__ out2, int M) {
    __shared__ float hjs[50 * 16];
    __shared__ float g1s[32 * 4];
    __shared__ float e1ws[4 * 32 * 16];
    __shared__ float e1bs[4 * 16];
    __shared__ float g2s[16 * 4];
    __shared__ float e2ws[4 * 16 * 2];
    __shared__ float e2bs[4 * 2];
    int tid = threadIdx.x;
    for (int t = tid; t < 800; t += 256) { int j = t >> 4, c = t & 15; hjs[t] = h2[nodes[j] * 16 + c]; }
    for (int t = tid; t < 128; t += 256) g1s[t] = gate1_w[t];
    for (int t = tid; t < 2048; t += 256) e1ws[t] = e1_w[t];
    for (int t = tid; t < 64; t += 256) e1bs[t] = e1_b[t];
    for (int t = tid; t < 64; t += 256) g2s[t] = gate2_w[t];
    for (int t = tid; t < 128; t += 256) e2ws[t] = e2_w[t];
    if (tid < 8) e2bs[tid] = e2_b[tid];
    __syncthreads();

    int m = blockIdx.x * 256 + tid;
    if (m >= M) return;
    int i = m / 50, j = m - i * 50;

    float xs[32];
    int ni = nodes[i];
    float4 a0 = *(const float4*)&h2[ni * 16];
    float4 a1 = *(const float4*)&h2[ni * 16 + 4];
    float4 a2 = *(const float4*)&h2[ni * 16 + 8];
    float4 a3 = *(const float4*)&h2[ni * 16 + 12];
    xs[0]=a0.x; xs[1]=a0.y; xs[2]=a0.z; xs[3]=a0.w;
    xs[4]=a1.x; xs[5]=a1.y; xs[6]=a1.z; xs[7]=a1.w;
    xs[8]=a2.x; xs[9]=a2.y; xs[10]=a2.z; xs[11]=a2.w;
    xs[12]=a3.x; xs[13]=a3.y; xs[14]=a3.z; xs[15]=a3.w;
    #pragma unroll
    for (int c = 0; c < 16; ++c) xs[16 + c] = hjs[j * 16 + c];

    #pragma unroll
    for (int c = 0; c < 32; c += 4)
        *(float4*)&out2[(size_t)m * 32 + c] = make_float4(xs[c], xs[c+1], xs[c+2], xs[c+3]);

    float g[4] = {0.f, 0.f, 0.f, 0.f};
    #pragma unroll
    for (int c = 0; c < 32; ++c) {
        float xv = xs[c];
        #pragma unroll
        for (int e = 0; e < 4; ++e) g[e] += xv * g1s[c * 4 + e];
    }
    int idx = 0; float best = g[0];
    #pragma unroll
    for (int e = 1; e < 4; ++e) if (g[e] > best) { best = g[e]; idx = e; }
    float z[16];
    #pragma unroll
    for (int o = 0; o < 16; ++o) {
        float a = e1bs[idx * 16 + o];
        #pragma unroll
        for (int c = 0; c < 32; ++c) a += xs[c] * e1ws[(idx * 32 + c) * 16 + o];
        z[o] = fmaxf(a, 0.f);
    }

    float g2[4] = {0.f, 0.f, 0.f, 0.f};
    #pragma unroll
    for (int c = 0; c < 16; ++c) {
        float zv = z[c];
        #pragma unroll
        for (int e = 0; e < 4; ++e) g2[e] += zv * g2s[c * 4 + e];
    }
    int idx2 = 0; float best2 = g2[0];
    #pragma unroll
    for (int e = 1; e < 4; ++e) if (g2[e] > best2) { best2 = g2[e]; idx2 = e; }
    float z2[2];
    #pragma unroll
    for (int o = 0; o < 2; ++o) {
        float a = e2bs[idx2 * 2 + o];
        #pragma unroll
        for (int c = 0; c < 16; ++c) a += z[c] * e2ws[(idx2 * 16 + c) * 2 + o];
        z2[o] = a;
    }

    float mx = fmaxf(z2[0], z2[1]);
    float l = logf(expf(z2[0] - mx) + expf(z2[1] - mx));
    out1[(size_t)m * 2 + 0] = z2[0] - mx - l;
    out1[(size_t)m * 2 + 1] = z2[1] - mx - l;
}

extern "C" void kernel_launch(void* const* d_in, const int* in_sizes, int n_in,
                              void* d_out, int out_size, void* d_ws, size_t ws_size,
                              hipStream_t stream) {
    const float* x       = (const float*)d_in[0];
    const float* w1      = (const float*)d_in[1];
    const float* b1      = (const float*)d_in[2];
    const float* w2      = (const float*)d_in[3];
    const float* b2      = (const float*)d_in[4];
    const float* gate1_w = (const float*)d_in[5];
    const float* e1_w    = (const float*)d_in[6];
    const float* e1_b    = (const float*)d_in[7];
    const float* gate2_w = (const float*)d_in[8];
    const float* e2_w    = (const float*)d_in[9];
    const float* e2_b    = (const float*)d_in[10];
    const int*   ei      = (const int*)d_in[11];
    const int*   nodes   = (const int*)d_in[12];

    const int n    = in_sizes[0] / 256;      // 100000
    const int nE   = in_sizes[11] / 2;       // 3200000
    const int nsel = in_sizes[12];           // 4096
    const int M    = nsel * 50;              // 204800
    const int nb   = (n + NPB - 1) / NPB;    // 1563

    size_t off = 0;
    auto alloc = [&](size_t bytes) -> void* {
        void* p = (char*)d_ws + off;
        off += (bytes + 255) & ~(size_t)255;
        return p;
    };
    float*  dis    = (float*)alloc((size_t)n * 4);
    int*    bhist  = (int*)alloc((size_t)nb * 4);
    int*    boffs  = (int*)alloc((size_t)(nb + 1) * 4);
    int*    gcur   = (int*)alloc((size_t)nb * 4);
    int*    noffs  = (int*)alloc((size_t)(n + 1) * 4);
    int*    keys   = (int*)alloc((size_t)nE * 4);   // becomes srcs after nodesort
    __half* hw1h   = (__half*)alloc((size_t)n * 32 * 2);
    __half* h1h    = (__half*)alloc((size_t)n * 32 * 2);
    float*  hw2s   = (float*)alloc((size_t)n * 16 * 4);
    float*  h2     = (float*)alloc((size_t)n * 16 * 4);
    if (off > ws_size) return;

    float* out1 = (float*)d_out;              // [M,2]
    float* out2 = out1 + (size_t)M * 2;       // [M,32]

    zero_kernel<<<(nb + 255) / 256, 256, 0, stream>>>(bhist, nb);
    histA_kernel<<<(nE + 4095) / 4096, 256, 0, stream>>>(ei, bhist, nE, nb);
    scanB_kernel<<<1, 256, 0, stream>>>(bhist, boffs, gcur, nb);
    scatterC_kernel<<<(nE + BATCH - 1) / BATCH, 256, 0, stream>>>(ei, gcur, keys, nE, nb);
    nodesort_kernel<<<nb, 256, 0, stream>>>(keys, boffs, noffs, dis, n, nb);
    hw1s_kernel<<<(n + 127) / 128, 256, 0, stream>>>(x, w1, dis, hw1h, n);
    gatherG1_kernel<<<(n + 7) / 8, 256, 0, stream>>>(hw1h, dis, keys, noffs, b1, h1h, n);
    gemm2_kernel<<<(n + 15) / 16, 256, 0, stream>>>(h1h, w2, dis, hw2s, n);
    gatherG2_kernel<<<(nsel + 15) / 16, 256, 0, stream>>>(hw2s, dis, keys, noffs, nodes, b2,
                                                          h2, nsel, n);
    pair_moe_kernel<<<(M + 255) / 256, 256, 0, stream>>>(h2, nodes, gate1_w, e1_w, e1_b,
                                                         gate2_w, e2_w, e2_b, out1, out2, M);
}

// Round 13
// 221.981 us; speedup vs baseline: 1.0444x; 1.0444x over previous
//
#include <hip/hip_runtime.h>
#include <hip/hip_fp16.h>
#include <math.h>

// ---------------------------------------------------------------------------
// GCNSim: 2-layer GCN. Bucket sort -> per-node CSR -> per-node register gather
// (32 lanes = 32 features per node, no LDS atomics).
// hw1h = fp16[(x@w1)*dis] rows of 64B; srcs[] = per-node-grouped neighbor ids.
// hw1s v5: 64 rows/block (grid 1564, ~6 blk/CU), reg double-buffered x chunks,
// thread=(row,kquarter), w1 via wave-uniform s_load, stride-68 LDS (b128-clean).
// Layer-2 aggregation computed only for the 4096 selected nodes.
// ---------------------------------------------------------------------------

#define NPB 64
#define NB_PAD 2048
#define BATCH 8192
#define NSCAP 12288

__global__ void zero_kernel(int* __restrict__ p, int c) {
    int i = blockIdx.x * 256 + threadIdx.x;
    if (i < c) p[i] = 0;
}

// ---- Pass A: per-bucket edge histogram (LDS-aggregated)
__global__ __launch_bounds__(256) void histA_kernel(const int* __restrict__ ei,
                                                    int* __restrict__ bhist, int nE, int nb) {
    __shared__ int h[NB_PAD];
    int tid = threadIdx.x;
    for (int t = tid; t < nb; t += 256) h[t] = 0;
    __syncthreads();
    int base = blockIdx.x * 4096;
    for (int t = tid; t < 4096; t += 256) {
        int e = base + t;
        if (e < nE) atomicAdd(&h[ei[nE + e] >> 6], 1);
    }
    __syncthreads();
    for (int t = tid; t < nb; t += 256) { int c = h[t]; if (c) atomicAdd(&bhist[t], c); }
}

// ---- Pass B: exclusive scan of bucket counts -> boffs[nb+1], gcur copy
__global__ __launch_bounds__(256) void scanB_kernel(const int* __restrict__ bhist,
                                                    int* __restrict__ boffs,
                                                    int* __restrict__ gcur, int nb) {
    int t = threadIdx.x;
    int v[8], s = 0;
    #pragma unroll
    for (int i = 0; i < 8; ++i) { int c = t * 8 + i; v[i] = (c < nb) ? bhist[c] : 0; s += v[i]; }
    int lane = t & 63, wid = t >> 6;
    int incl = s;
    for (int d = 1; d < 64; d <<= 1) { int u = __shfl_up(incl, (unsigned)d, 64); if (lane >= d) incl += u; }
    __shared__ int ws[4];
    if (lane == 63) ws[wid] = incl;
    __syncthreads();
    int add = 0;
    for (int w = 0; w < wid; ++w) add += ws[w];
    incl += add;
    int excl = incl - s;
    #pragma unroll
    for (int i = 0; i < 8; ++i) {
        int c = t * 8 + i;
        if (c < nb) { boffs[c] = excl; gcur[c] = excl; }
        excl += v[i];
    }
    if (t == 0) boffs[nb] = ws[0] + ws[1] + ws[2] + ws[3];
}

// ---- Pass C: value-scatter of packed keys into bucket regions.
__global__ __launch_bounds__(256) void scatterC_kernel(const int* __restrict__ ei,
                                                       int* __restrict__ gcur,
                                                       int* __restrict__ keys, int nE, int nb) {
    __shared__ int kbuf[BATCH];              // 32 KB
    __shared__ unsigned short kbk[BATCH];    // 16 KB
    __shared__ int lstart[NB_PAD];           // 8 KB
    __shared__ int cursor[NB_PAD];           // 8 KB
    __shared__ int gbase[NB_PAD];            // 8 KB
    __shared__ int ws2[4];
    int tid = threadIdx.x;
    int base = blockIdx.x * BATCH;
    int cnt = nE - base; if (cnt > BATCH) cnt = BATCH;
    for (int t = tid; t < nb; t += 256) lstart[t] = 0;
    __syncthreads();
    for (int t = tid; t < cnt; t += 256)
        atomicAdd(&lstart[ei[nE + base + t] >> 6], 1);
    __syncthreads();
    {
        int v[8], s = 0;
        #pragma unroll
        for (int i = 0; i < 8; ++i) { int c = tid * 8 + i; v[i] = (c < nb) ? lstart[c] : 0; s += v[i]; }
        int lane = tid & 63, wid = tid >> 6;
        int incl = s;
        for (int d = 1; d < 64; d <<= 1) { int u = __shfl_up(incl, (unsigned)d, 64); if (lane >= d) incl += u; }
        if (lane == 63) ws2[wid] = incl;
        __syncthreads();
        int add = 0;
        for (int w = 0; w < wid; ++w) add += ws2[w];
        incl += add;
        int excl = incl - s;
        #pragma unroll
        for (int i = 0; i < 8; ++i) {
            int c = tid * 8 + i;
            if (c < nb) { lstart[c] = excl; cursor[c] = excl; }
            excl += v[i];
        }
    }
    __syncthreads();
    for (int t = tid; t < nb; t += 256) {
        int e = (t == nb - 1) ? cnt : lstart[t + 1];
        int c = e - lstart[t];
        gbase[t] = c ? atomicAdd(&gcur[t], c) : 0;
    }
    for (int t = tid; t < cnt; t += 256) {
        int d = ei[nE + base + t];
        int s = ei[base + t];
        int b = d >> 6;
        int pos = atomicAdd(&cursor[b], 1);
        kbuf[pos] = s | ((d & 63) << 17);
        kbk[pos] = (unsigned short)b;
    }
    __syncthreads();
    for (int j = tid; j < cnt; j += 256) {
        int b = kbk[j];
        keys[gbase[b] + (j - lstart[b])] = kbuf[j];
    }
}

// ---- nodesort: bucket -> per-node CSR (in-place via LDS), noffs, dis
__global__ __launch_bounds__(256) void nodesort_kernel(int* __restrict__ keys,
                                                       const int* __restrict__ boffs,
                                                       int* __restrict__ noffs,
                                                       float* __restrict__ dis,
                                                       int n, int nbuck) {
    __shared__ int kb[NSCAP];     // 48 KB
    __shared__ int cnt[NPB], cur[NPB];
    int tid = threadIdx.x, b = blockIdx.x;
    int off = boffs[b], end = boffs[b + 1];
    int m = end - off; if (m > NSCAP) m = NSCAP;
    if (tid < NPB) cnt[tid] = 0;
    __syncthreads();
    for (int t = tid; t < m; t += 256) {
        int k = keys[off + t];
        kb[t] = k;
        atomicAdd(&cnt[k >> 17], 1);
    }
    __syncthreads();
    if (tid < NPB) {
        int v = cnt[tid];
        int incl = v;
        for (int d = 1; d < 64; d <<= 1) { int u = __shfl_up(incl, (unsigned)d, 64); if (tid >= d) incl += u; }
        int excl = incl - v;
        cur[tid] = excl;
        int node = b * NPB + tid;
        if (node < n) {
            noffs[node] = off + excl;
            dis[node] = rsqrtf((float)(v + 1));
        }
    }
    __syncthreads();
    for (int t = tid; t < m; t += 256) {
        int k = kb[t];
        int pos = atomicAdd(&cur[k >> 17], 1);
        keys[off + pos] = k & 0x1FFFF;
    }
    if (b == nbuck - 1 && tid == 0) noffs[n] = end;
}

// ---- hw1h = fp16[(x @ w1) * dis]: 64 rows/block, thread = (row, kquarter).
// Register double-buffer: prefetch chunk ch+1 while computing ch.
// xs stride 68 floats = 17x16B -> conflict-free ds_read_b128.
__global__ __launch_bounds__(256) void hw1s_kernel(const float* __restrict__ x,
                                                   const float* __restrict__ w1,
                                                   const float* __restrict__ dis,
                                                   __half* __restrict__ hw1h, int n) {
    __shared__ float xs[64 * 68];   // 17.4 KB
    int tid = threadIdx.x;
    int row0 = blockIdx.x * 64;
    int r = tid & 63;
    int khs = __builtin_amdgcn_readfirstlane((tid >> 6) * 8);  // wave-uniform k-quarter
    float acc[8];
    #pragma unroll
    for (int k = 0; k < 8; ++k) acc[k] = 0.f;

    int lr = tid >> 2;                 // load row 0..63
    int lc0 = (tid & 3) << 4;          // load col base 0,16,32,48
    float4 pf[4];

    // prefetch chunk 0
    #pragma unroll
    for (int i = 0; i < 4; ++i) {
        int row = row0 + lr;
        pf[i] = (row < n) ? *(const float4*)&x[(size_t)row * 256 + 0 + lc0 + i * 4]
                          : make_float4(0.f, 0.f, 0.f, 0.f);
    }

    for (int ch = 0; ch < 4; ++ch) {
        int cc0 = ch * 64;
        // write prefetched chunk to LDS
        #pragma unroll
        for (int i = 0; i < 4; ++i)
            *(float4*)&xs[lr * 68 + lc0 + i * 4] = pf[i];
        __syncthreads();
        // issue next chunk's loads (retire during compute)
        if (ch < 3) {
            int cn = cc0 + 64;
            #pragma unroll
            for (int i = 0; i < 4; ++i) {
                int row = row0 + lr;
                pf[i] = (row < n) ? *(const float4*)&x[(size_t)row * 256 + cn + lc0 + i * 4]
                                  : make_float4(0.f, 0.f, 0.f, 0.f);
            }
        }
        // compute
        #pragma unroll 4
        for (int cg = 0; cg < 16; ++cg) {
            float4 xv = *(float4*)&xs[r * 68 + cg * 4];
            const float* wr = &w1[(size_t)(cc0 + cg * 4) * 32 + khs];   // uniform -> s_load
            #pragma unroll
            for (int k = 0; k < 8; ++k) acc[k] = fmaf(xv.x, wr[k], acc[k]);
            #pragma unroll
            for (int k = 0; k < 8; ++k) acc[k] = fmaf(xv.y, wr[32 + k], acc[k]);
            #pragma unroll
            for (int k = 0; k < 8; ++k) acc[k] = fmaf(xv.z, wr[64 + k], acc[k]);
            #pragma unroll
            for (int k = 0; k < 8; ++k) acc[k] = fmaf(xv.w, wr[96 + k], acc[k]);
        }
        __syncthreads();
    }
    int row = row0 + r;
    if (row < n) {
        float dn = dis[row];
        __half2 h[4];
        #pragma unroll
        for (int k = 0; k < 4; ++k)
            h[k] = __floats2half2_rn(acc[2 * k] * dn, acc[2 * k + 1] * dn);
        *(float4*)&hw1h[(size_t)row * 32 + khs] = *(float4*)&h[0];
    }
}

// ---- gatherG1: per-node register gather (32 lanes = 32 features), ReLU -> h1h
__global__ __launch_bounds__(256) void gatherG1_kernel(const __half* __restrict__ hw1h,
                                                       const float* __restrict__ dis,
                                                       const int* __restrict__ srcs,
                                                       const int* __restrict__ noffs,
                                                       const float* __restrict__ b1,
                                                       __half* __restrict__ h1h, int n) {
    int tid = threadIdx.x;
    int g = tid >> 5, k = tid & 31;
    int node = blockIdx.x * 8 + g;
    if (node >= n) return;
    int off = noffs[node], end = noffs[node + 1];
    float acc = 0.f;
    int e = off;
    for (; e + 8 <= end; e += 8) {
        int s0 = srcs[e],     s1 = srcs[e + 1], s2 = srcs[e + 2], s3 = srcs[e + 3];
        int s4 = srcs[e + 4], s5 = srcs[e + 5], s6 = srcs[e + 6], s7 = srcs[e + 7];
        float v0 = __half2float(hw1h[(size_t)s0 * 32 + k]);
        float v1 = __half2float(hw1h[(size_t)s1 * 32 + k]);
        float v2 = __half2float(hw1h[(size_t)s2 * 32 + k]);
        float v3 = __half2float(hw1h[(size_t)s3 * 32 + k]);
        float v4 = __half2float(hw1h[(size_t)s4 * 32 + k]);
        float v5 = __half2float(hw1h[(size_t)s5 * 32 + k]);
        float v6 = __half2float(hw1h[(size_t)s6 * 32 + k]);
        float v7 = __half2float(hw1h[(size_t)s7 * 32 + k]);
        acc += ((v0 + v1) + (v2 + v3)) + ((v4 + v5) + (v6 + v7));
    }
    for (; e < end; ++e)
        acc += __half2float(hw1h[(size_t)srcs[e] * 32 + k]);
    float dn = dis[node];
    float self = __half2float(hw1h[(size_t)node * 32 + k]);
    float h = fmaxf(dn * (acc + self) + b1[k], 0.f);
    h1h[(size_t)node * 32 + k] = __float2half(h);
}

// ---- gemm2: hw2s = (h1 @ w2) * dis   [N,32]x[32,16] -> [N,16] f32
__global__ __launch_bounds__(256) void gemm2_kernel(const __half* __restrict__ h1h,
                                                    const float* __restrict__ w2,
                                                    const float* __restrict__ dis,
                                                    float* __restrict__ hw2s, int n) {
    __shared__ float w2s[512];
    __shared__ float h1s[16][33];
    int tid = threadIdx.x;
    for (int t = tid; t < 512; t += 256) w2s[t] = w2[t];
    int node0 = blockIdx.x * 16;
    for (int t = tid; t < 512; t += 256) {
        int r = t >> 5, c = t & 31;
        int nd = node0 + r;
        h1s[r][c] = (nd < n) ? __half2float(h1h[(size_t)nd * 32 + c]) : 0.f;
    }
    __syncthreads();
    int r = tid >> 4, j = tid & 15;
    int nd = node0 + r;
    if (nd < n) {
        float a = 0.f;
        #pragma unroll
        for (int c = 0; c < 32; ++c) a += h1s[r][c] * w2s[c * 16 + j];
        hw2s[(size_t)nd * 16 + j] = a * dis[nd];
    }
}

// ---- gatherG2: layer-2 aggregation for SELECTED nodes only (16 lanes/node)
__global__ __launch_bounds__(256) void gatherG2_kernel(const float* __restrict__ hw2s,
                                                       const float* __restrict__ dis,
                                                       const int* __restrict__ srcs,
                                                       const int* __restrict__ noffs,
                                                       const int* __restrict__ nodes,
                                                       const float* __restrict__ b2,
                                                       float* __restrict__ h2, int nsel, int n) {
    int tid = threadIdx.x;
    int slot = tid >> 4, j = tid & 15;
    int i = blockIdx.x * 16 + slot;
    if (i >= nsel) return;
    int node = nodes[i];
    int off = noffs[node], end = noffs[node + 1];
    float acc = 0.f;
    int e = off;
    for (; e + 4 <= end; e += 4) {
        int s0 = srcs[e], s1 = srcs[e + 1], s2 = srcs[e + 2], s3 = srcs[e + 3];
        float v0 = hw2s[(size_t)s0 * 16 + j];
        float v1 = hw2s[(size_t)s1 * 16 + j];
        float v2 = hw2s[(size_t)s2 * 16 + j];
        float v3 = hw2s[(size_t)s3 * 16 + j];
        acc += (v0 + v1) + (v2 + v3);
    }
    for (; e < end; ++e) acc += hw2s[(size_t)srcs[e] * 16 + j];
    h2[(size_t)node * 16 + j] = dis[node] * (acc + hw2s[(size_t)node * 16 + j]) + b2[j];
}

// ---- pairwise concat + MoE1 + MoE2 + log_softmax
__global__ __launch_bounds__(256) void pair_moe_kernel(const float* __restrict__ h2,
                                                       const int* __restrict__ nodes,
                                                       const float* __restrict__ gate1_w,
                                                       const float* __restrict__ e1_w,
                                                       const float* __restrict__ e1_b,
                                                       const float* __restrict__ gate2_w,
                                                       const float* __restrict__ e2_w,
                                                       const float* __restrict__ e2_b,
                                                       float* __restrict__ out1,
                                                       float* __restrict__ out2, int M) {
    __shared__ float hjs[50 * 16];
    __shared__ float g1s[32 * 4];
    __shared__ float e1ws[4 * 32 * 16];
    __shared__ float e1bs[4 * 16];
    __shared__ float g2s[16 * 4];
    __shared__ float e2ws[4 * 16 * 2];
    __shared__ float e2bs[4 * 2];
    int tid = threadIdx.x;
    for (int t = tid; t < 800; t += 256) { int j = t >> 4, c = t & 15; hjs[t] = h2[nodes[j] * 16 + c]; }
    for (int t = tid; t < 128; t += 256) g1s[t] = gate1_w[t];
    for (int t = tid; t < 2048; t += 256) e1ws[t] = e1_w[t];
    for (int t = tid; t < 64; t += 256) e1bs[t] = e1_b[t];
    for (int t = tid; t < 64; t += 256) g2s[t] = gate2_w[t];
    for (int t = tid; t < 128; t += 256) e2ws[t] = e2_w[t];
    if (tid < 8) e2bs[tid] = e2_b[tid];
    __syncthreads();

    int m = blockIdx.x * 256 + tid;
    if (m >= M) return;
    int i = m / 50, j = m - i * 50;

    float xs[32];
    int ni = nodes[i];
    float4 a0 = *(const float4*)&h2[ni * 16];
    float4 a1 = *(const float4*)&h2[ni * 16 + 4];
    float4 a2 = *(const float4*)&h2[ni * 16 + 8];
    float4 a3 = *(const float4*)&h2[ni * 16 + 12];
    xs[0]=a0.x; xs[1]=a0.y; xs[2]=a0.z; xs[3]=a0.w;
    xs[4]=a1.x; xs[5]=a1.y; xs[6]=a1.z; xs[7]=a1.w;
    xs[8]=a2.x; xs[9]=a2.y; xs[10]=a2.z; xs[11]=a2.w;
    xs[12]=a3.x; xs[13]=a3.y; xs[14]=a3.z; xs[15]=a3.w;
    #pragma unroll
    for (int c = 0; c < 16; ++c) xs[16 + c] = hjs[j * 16 + c];

    #pragma unroll
    for (int c = 0; c < 32; c += 4)
        *(float4*)&out2[(size_t)m * 32 + c] = make_float4(xs[c], xs[c+1], xs[c+2], xs[c+3]);

    float g[4] = {0.f, 0.f, 0.f, 0.f};
    #pragma unroll
    for (int c = 0; c < 32; ++c) {
        float xv = xs[c];
        #pragma unroll
        for (int e = 0; e < 4; ++e) g[e] += xv * g1s[c * 4 + e];
    }
    int idx = 0; float best = g[0];
    #pragma unroll
    for (int e = 1; e < 4; ++e) if (g[e] > best) { best = g[e]; idx = e; }
    float z[16];
    #pragma unroll
    for (int o = 0; o < 16; ++o) {
        float a = e1bs[idx * 16 + o];
        #pragma unroll
        for (int c = 0; c < 32; ++c) a += xs[c] * e1ws[(idx * 32 + c) * 16 + o];
        z[o] = fmaxf(a, 0.f);
    }

    float g2[4] = {0.f, 0.f, 0.f, 0.f};
    #pragma unroll
    for (int c = 0; c < 16; ++c) {
        float zv = z[c];
        #pragma unroll
        for (int e = 0; e < 4; ++e) g2[e] += zv * g2s[c * 4 + e];
    }
    int idx2 = 0; float best2 = g2[0];
    #pragma unroll
    for (int e = 1; e < 4; ++e) if (g2[e] > best2) { best2 = g2[e]; idx2 = e; }
    float z2[2];
    #pragma unroll
    for (int o = 0; o < 2; ++o) {
        float a = e2bs[idx2 * 2 + o];
        #pragma unroll
        for (int c = 0; c < 16; ++c) a += z[c] * e2ws[(idx2 * 16 + c) * 2 + o];
        z2[o] = a;
    }

    float mx = fmaxf(z2[0], z2[1]);
    float l = logf(expf(z2[0] - mx) + expf(z2[1] - mx));
    out1[(size_t)m * 2 + 0] = z2[0] - mx - l;
    out1[(size_t)m * 2 + 1] = z2[1] - mx - l;
}

extern "C" void kernel_launch(void* const* d_in, const int* in_sizes, int n_in,
                              void* d_out, int out_size, void* d_ws, size_t ws_size,
                              hipStream_t stream) {
    const float* x       = (const float*)d_in[0];
    const float* w1      = (const float*)d_in[1];
    const float* b1      = (const float*)d_in[2];
    const float* w2      = (const float*)d_in[3];
    const float* b2      = (const float*)d_in[4];
    const float* gate1_w = (const float*)d_in[5];
    const float* e1_w    = (const float*)d_in[6];
    const float* e1_b    = (const float*)d_in[7];
    const float* gate2_w = (const float*)d_in[8];
    const float* e2_w    = (const float*)d_in[9];
    const float* e2_b    = (const float*)d_in[10];
    const int*   ei      = (const int*)d_in[11];
    const int*   nodes   = (const int*)d_in[12];

    const int n    = in_sizes[0] / 256;      // 100000
    const int nE   = in_sizes[11] / 2;       // 3200000
    const int nsel = in_sizes[12];           // 4096
    const int M    = nsel * 50;              // 204800
    const int nb   = (n + NPB - 1) / NPB;    // 1563

    size_t off = 0;
    auto alloc = [&](size_t bytes) -> void* {
        void* p = (char*)d_ws + off;
        off += (bytes + 255) & ~(size_t)255;
        return p;
    };
    float*  dis    = (float*)alloc((size_t)n * 4);
    int*    bhist  = (int*)alloc((size_t)nb * 4);
    int*    boffs  = (int*)alloc((size_t)(nb + 1) * 4);
    int*    gcur   = (int*)alloc((size_t)nb * 4);
    int*    noffs  = (int*)alloc((size_t)(n + 1) * 4);
    int*    keys   = (int*)alloc((size_t)nE * 4);   // becomes srcs after nodesort
    __half* hw1h   = (__half*)alloc((size_t)n * 32 * 2);
    __half* h1h    = (__half*)alloc((size_t)n * 32 * 2);
    float*  hw2s   = (float*)alloc((size_t)n * 16 * 4);
    float*  h2     = (float*)alloc((size_t)n * 16 * 4);
    if (off > ws_size) return;

    float* out1 = (float*)d_out;              // [M,2]
    float* out2 = out1 + (size_t)M * 2;       // [M,32]

    zero_kernel<<<(nb + 255) / 256, 256, 0, stream>>>(bhist, nb);
    histA_kernel<<<(nE + 4095) / 4096, 256, 0, stream>>>(ei, bhist, nE, nb);
    scanB_kernel<<<1, 256, 0, stream>>>(bhist, boffs, gcur, nb);
    scatterC_kernel<<<(nE + BATCH - 1) / BATCH, 256, 0, stream>>>(ei, gcur, keys, nE, nb);
    nodesort_kernel<<<nb, 256, 0, stream>>>(keys, boffs, noffs, dis, n, nb);
    hw1s_kernel<<<(n + 63) / 64, 256, 0, stream>>>(x, w1, dis, hw1h, n);
    gatherG1_kernel<<<(n + 7) / 8, 256, 0, stream>>>(hw1h, dis, keys, noffs, b1, h1h, n);
    gemm2_kernel<<<(n + 15) / 16, 256, 0, stream>>>(h1h, w2, dis, hw2s, n);
    gatherG2_kernel<<<(nsel + 15) / 16, 256, 0, stream>>>(hw2s, dis, keys, noffs, nodes, b2,
                                                          h2, nsel, n);
    pair_moe_kernel<<<(M + 255) / 256, 256, 0, stream>>>(h2, nodes, gate1_w, e1_w, e1_b,
                                                         gate2_w, e2_w, e2_b, out1, out2, M);
}

// Round 14
// 208.711 us; speedup vs baseline: 1.1108x; 1.0636x over previous
//
#include <hip/hip_runtime.h>
#include <hip/hip_fp16.h>
#include <math.h>

// ---------------------------------------------------------------------------
// GCNSim: 2-layer GCN. Bucket sort -> per-node CSR -> per-node register gather.
// hw1s v6: MFMA (16x16x32 f16) GEMM — per wave a 16x32 tile over K=256;
// w1 fragments register-resident; x streamed+cvt. gatherG1 fuses the @w2
// projection (h1 staged in LDS). Layer-2 agg only for selected nodes.
// ---------------------------------------------------------------------------

#define NPB 64
#define NB_PAD 2048
#define BATCH 8192
#define NSCAP 12288

typedef _Float16 half8 __attribute__((ext_vector_type(8)));
typedef float f32x4 __attribute__((ext_vector_type(4)));

__global__ void zero_kernel(int* __restrict__ p, int c) {
    int i = blockIdx.x * 256 + threadIdx.x;
    if (i < c) p[i] = 0;
}

// ---- Pass A: per-bucket edge histogram (LDS-aggregated)
__global__ __launch_bounds__(256) void histA_kernel(const int* __restrict__ ei,
                                                    int* __restrict__ bhist, int nE, int nb) {
    __shared__ int h[NB_PAD];
    int tid = threadIdx.x;
    for (int t = tid; t < nb; t += 256) h[t] = 0;
    __syncthreads();
    int base = blockIdx.x * 4096;
    for (int t = tid; t < 4096; t += 256) {
        int e = base + t;
        if (e < nE) atomicAdd(&h[ei[nE + e] >> 6], 1);
    }
    __syncthreads();
    for (int t = tid; t < nb; t += 256) { int c = h[t]; if (c) atomicAdd(&bhist[t], c); }
}

// ---- Pass B: exclusive scan of bucket counts -> boffs[nb+1], gcur copy
__global__ __launch_bounds__(256) void scanB_kernel(const int* __restrict__ bhist,
                                                    int* __restrict__ boffs,
                                                    int* __restrict__ gcur, int nb) {
    int t = threadIdx.x;
    int v[8], s = 0;
    #pragma unroll
    for (int i = 0; i < 8; ++i) { int c = t * 8 + i; v[i] = (c < nb) ? bhist[c] : 0; s += v[i]; }
    int lane = t & 63, wid = t >> 6;
    int incl = s;
    for (int d = 1; d < 64; d <<= 1) { int u = __shfl_up(incl, (unsigned)d, 64); if (lane >= d) incl += u; }
    __shared__ int ws[4];
    if (lane == 63) ws[wid] = incl;
    __syncthreads();
    int add = 0;
    for (int w = 0; w < wid; ++w) add += ws[w];
    incl += add;
    int excl = incl - s;
    #pragma unroll
    for (int i = 0; i < 8; ++i) {
        int c = t * 8 + i;
        if (c < nb) { boffs[c] = excl; gcur[c] = excl; }
        excl += v[i];
    }
    if (t == 0) boffs[nb] = ws[0] + ws[1] + ws[2] + ws[3];
}

// ---- Pass C: value-scatter of packed keys into bucket regions.
__global__ __launch_bounds__(256) void scatterC_kernel(const int* __restrict__ ei,
                                                       int* __restrict__ gcur,
                                                       int* __restrict__ keys, int nE, int nb) {
    __shared__ int kbuf[BATCH];              // 32 KB
    __shared__ unsigned short kbk[BATCH];    // 16 KB
    __shared__ int lstart[NB_PAD];           // 8 KB
    __shared__ int cursor[NB_PAD];           // 8 KB
    __shared__ int gbase[NB_PAD];            // 8 KB
    __shared__ int ws2[4];
    int tid = threadIdx.x;
    int base = blockIdx.x * BATCH;
    int cnt = nE - base; if (cnt > BATCH) cnt = BATCH;
    for (int t = tid; t < nb; t += 256) lstart[t] = 0;
    __syncthreads();
    for (int t = tid; t < cnt; t += 256)
        atomicAdd(&lstart[ei[nE + base + t] >> 6], 1);
    __syncthreads();
    {
        int v[8], s = 0;
        #pragma unroll
        for (int i = 0; i < 8; ++i) { int c = tid * 8 + i; v[i] = (c < nb) ? lstart[c] : 0; s += v[i]; }
        int lane = tid & 63, wid = tid >> 6;
        int incl = s;
        for (int d = 1; d < 64; d <<= 1) { int u = __shfl_up(incl, (unsigned)d, 64); if (lane >= d) incl += u; }
        if (lane == 63) ws2[wid] = incl;
        __syncthreads();
        int add = 0;
        for (int w = 0; w < wid; ++w) add += ws2[w];
        incl += add;
        int excl = incl - s;
        #pragma unroll
        for (int i = 0; i < 8; ++i) {
            int c = tid * 8 + i;
            if (c < nb) { lstart[c] = excl; cursor[c] = excl; }
            excl += v[i];
        }
    }
    __syncthreads();
    for (int t = tid; t < nb; t += 256) {
        int e = (t == nb - 1) ? cnt : lstart[t + 1];
        int c = e - lstart[t];
        gbase[t] = c ? atomicAdd(&gcur[t], c) : 0;
    }
    for (int t = tid; t < cnt; t += 256) {
        int d = ei[nE + base + t];
        int s = ei[base + t];
        int b = d >> 6;
        int pos = atomicAdd(&cursor[b], 1);
        kbuf[pos] = s | ((d & 63) << 17);
        kbk[pos] = (unsigned short)b;
    }
    __syncthreads();
    for (int j = tid; j < cnt; j += 256) {
        int b = kbk[j];
        keys[gbase[b] + (j - lstart[b])] = kbuf[j];
    }
}

// ---- nodesort: bucket -> per-node CSR (in-place via LDS), noffs, dis
__global__ __launch_bounds__(256) void nodesort_kernel(int* __restrict__ keys,
                                                       const int* __restrict__ boffs,
                                                       int* __restrict__ noffs,
                                                       float* __restrict__ dis,
                                                       int n, int nbuck) {
    __shared__ int kb[NSCAP];     // 48 KB
    __shared__ int cnt[NPB], cur[NPB];
    int tid = threadIdx.x, b = blockIdx.x;
    int off = boffs[b], end = boffs[b + 1];
    int m = end - off; if (m > NSCAP) m = NSCAP;
    if (tid < NPB) cnt[tid] = 0;
    __syncthreads();
    for (int t = tid; t < m; t += 256) {
        int k = keys[off + t];
        kb[t] = k;
        atomicAdd(&cnt[k >> 17], 1);
    }
    __syncthreads();
    if (tid < NPB) {
        int v = cnt[tid];
        int incl = v;
        for (int d = 1; d < 64; d <<= 1) { int u = __shfl_up(incl, (unsigned)d, 64); if (tid >= d) incl += u; }
        int excl = incl - v;
        cur[tid] = excl;
        int node = b * NPB + tid;
        if (node < n) {
            noffs[node] = off + excl;
            dis[node] = rsqrtf((float)(v + 1));
        }
    }
    __syncthreads();
    for (int t = tid; t < m; t += 256) {
        int k = kb[t];
        int pos = atomicAdd(&cur[k >> 17], 1);
        keys[off + pos] = k & 0x1FFFF;
    }
    if (b == nbuck - 1 && tid == 0) noffs[n] = end;
}

// ---- hw1h = fp16[(x @ w1) * dis] via MFMA 16x16x32 f16.
// Per wave: 16-row block, N=32 (2 tiles), K=256 (8 chunks) = 16 mfma.
// B (w1) fragments register-resident; A (x) streamed f32 -> cvt f16.
// A/B share the same k-mapping so any k-permutation cancels; D layout per m89.
__global__ __launch_bounds__(256) void hw1s_kernel(const float* __restrict__ x,
                                                   const float* __restrict__ w1,
                                                   const float* __restrict__ dis,
                                                   __half* __restrict__ hw1h, int n) {
    int tid = threadIdx.x;
    int lane = tid & 63;
    int wv = blockIdx.x * 4 + (tid >> 6);
    int nw = gridDim.x * 4;
    int mr = lane & 15, grp = lane >> 4;

    // B fragments: bf[nt][kc][e] = w1[kc*32 + grp*8 + e][nt*16 + mr]
    half8 bf0[8], bf1[8];
    #pragma unroll
    for (int kc = 0; kc < 8; ++kc) {
        half8 b0, b1v;
        #pragma unroll
        for (int e = 0; e < 8; ++e) {
            int k = kc * 32 + grp * 8 + e;
            b0[e]  = (_Float16)w1[k * 32 + mr];
            b1v[e] = (_Float16)w1[k * 32 + 16 + mr];
        }
        bf0[kc] = b0; bf1[kc] = b1v;
    }

    int nblk = (n + 15) >> 4;
    for (int blk = wv; blk < nblk; blk += nw) {
        int row = (blk << 4) + mr;
        int rowc = (row < n) ? row : n - 1;
        const float* xr = &x[(size_t)rowc * 256 + grp * 8];
        half8 af[8];
        #pragma unroll
        for (int kc = 0; kc < 8; ++kc) {
            float4 u = *(const float4*)&xr[kc * 32];
            float4 v = *(const float4*)&xr[kc * 32 + 4];
            half8 a;
            a[0] = (_Float16)u.x; a[1] = (_Float16)u.y;
            a[2] = (_Float16)u.z; a[3] = (_Float16)u.w;
            a[4] = (_Float16)v.x; a[5] = (_Float16)v.y;
            a[6] = (_Float16)v.z; a[7] = (_Float16)v.w;
            af[kc] = a;
        }
        f32x4 acc0 = {0.f, 0.f, 0.f, 0.f}, acc1 = {0.f, 0.f, 0.f, 0.f};
        #pragma unroll
        for (int kc = 0; kc < 8; ++kc)
            acc0 = __builtin_amdgcn_mfma_f32_16x16x32_f16(af[kc], bf0[kc], acc0, 0, 0, 0);
        #pragma unroll
        for (int kc = 0; kc < 8; ++kc)
            acc1 = __builtin_amdgcn_mfma_f32_16x16x32_f16(af[kc], bf1[kc], acc1, 0, 0, 0);
        // D: n-idx = mr, m = grp*4 + i  (m89-verified)
        #pragma unroll
        for (int i = 0; i < 4; ++i) {
            int orow = (blk << 4) + grp * 4 + i;
            if (orow < n) {
                float dn = dis[orow];
                hw1h[(size_t)orow * 32 + mr]      = __float2half(acc0[i] * dn);
                hw1h[(size_t)orow * 32 + 16 + mr] = __float2half(acc1[i] * dn);
            }
        }
    }
}

// ---- gatherG1: per-node register gather (32 lanes = 32 features), ReLU,
//      then fused (h1 @ w2) * dis -> hw2s via LDS staging.
__global__ __launch_bounds__(256) void gatherG1_kernel(const __half* __restrict__ hw1h,
                                                       const float* __restrict__ dis,
                                                       const int* __restrict__ srcs,
                                                       const int* __restrict__ noffs,
                                                       const float* __restrict__ b1,
                                                       const float* __restrict__ w2,
                                                       float* __restrict__ hw2s, int n) {
    __shared__ float h1s[8][33];
    __shared__ float w2s[512];
    int tid = threadIdx.x;
    for (int t = tid; t < 512; t += 256) w2s[t] = w2[t];
    int g = tid >> 5, k = tid & 31;
    int node = blockIdx.x * 8 + g;
    float h = 0.f;
    if (node < n) {
        int off = noffs[node], end = noffs[node + 1];
        float acc = 0.f;
        int e = off;
        for (; e + 8 <= end; e += 8) {
            int s0 = srcs[e],     s1 = srcs[e + 1], s2 = srcs[e + 2], s3 = srcs[e + 3];
            int s4 = srcs[e + 4], s5 = srcs[e + 5], s6 = srcs[e + 6], s7 = srcs[e + 7];
            float v0 = __half2float(hw1h[(size_t)s0 * 32 + k]);
            float v1 = __half2float(hw1h[(size_t)s1 * 32 + k]);
            float v2 = __half2float(hw1h[(size_t)s2 * 32 + k]);
            float v3 = __half2float(hw1h[(size_t)s3 * 32 + k]);
            float v4 = __half2float(hw1h[(size_t)s4 * 32 + k]);
            float v5 = __half2float(hw1h[(size_t)s5 * 32 + k]);
            float v6 = __half2float(hw1h[(size_t)s6 * 32 + k]);
            float v7 = __half2float(hw1h[(size_t)s7 * 32 + k]);
            acc += ((v0 + v1) + (v2 + v3)) + ((v4 + v5) + (v6 + v7));
        }
        for (; e < end; ++e)
            acc += __half2float(hw1h[(size_t)srcs[e] * 32 + k]);
        float dn = dis[node];
        float self = __half2float(hw1h[(size_t)node * 32 + k]);
        h = fmaxf(dn * (acc + self) + b1[k], 0.f);
    }
    h1s[g][k] = h;
    __syncthreads();
    if (tid < 128) {
        int gg = tid >> 4, j = tid & 15;
        int nd = blockIdx.x * 8 + gg;
        if (nd < n) {
            float a = 0.f;
            #pragma unroll
            for (int c = 0; c < 32; ++c) a += h1s[gg][c] * w2s[c * 16 + j];
            hw2s[(size_t)nd * 16 + j] = a * dis[nd];
        }
    }
}

// ---- gatherG2: layer-2 aggregation for SELECTED nodes only (16 lanes/node)
__global__ __launch_bounds__(256) void gatherG2_kernel(const float* __restrict__ hw2s,
                                                       const float* __restrict__ dis,
                                                       const int* __restrict__ srcs,
                                                       const int* __restrict__ noffs,
                                                       const int* __restrict__ nodes,
                                                       const float* __restrict__ b2,
                                                       float* __restrict__ h2, int nsel, int n) {
    int tid = threadIdx.x;
    int slot = tid >> 4, j = tid & 15;
    int i = blockIdx.x * 16 + slot;
    if (i >= nsel) return;
    int node = nodes[i];
    int off = noffs[node], end = noffs[node + 1];
    float acc = 0.f;
    int e = off;
    for (; e + 4 <= end; e += 4) {
        int s0 = srcs[e], s1 = srcs[e + 1], s2 = srcs[e + 2], s3 = srcs[e + 3];
        float v0 = hw2s[(size_t)s0 * 16 + j];
        float v1 = hw2s[(size_t)s1 * 16 + j];
        float v2 = hw2s[(size_t)s2 * 16 + j];
        float v3 = hw2s[(size_t)s3 * 16 + j];
        acc += (v0 + v1) + (v2 + v3);
    }
    for (; e < end; ++e) acc += hw2s[(size_t)srcs[e] * 16 + j];
    h2[(size_t)node * 16 + j] = dis[node] * (acc + hw2s[(size_t)node * 16 + j]) + b2[j];
}

// ---- pairwise concat + MoE1 + MoE2 + log_softmax
__global__ __launch_bounds__(256) void pair_moe_kernel(const float* __restrict__ h2,
                                                       const int* __restrict__ nodes,
                                                       const float* __restrict__ gate1_w,
                                                       const float* __restrict__ e1_w,
                                                       const float* __restrict__ e1_b,
                                                       const float* __restrict__ gate2_w,
                                                       const float* __restrict__ e2_w,
                                                       const float* __restrict__ e2_b,
                                                       float* __restrict__ out1,
                                                       float* __restrict__ out2, int M) {
    __shared__ float hjs[50 * 16];
    __shared__ float g1s[32 * 4];
    __shared__ float e1ws[4 * 32 * 16];
    __shared__ float e1bs[4 * 16];
    __shared__ float g2s[16 * 4];
    __shared__ float e2ws[4 * 16 * 2];
    __shared__ float e2bs[4 * 2];
    int tid = threadIdx.x;
    for (int t = tid; t < 800; t += 256) { int j = t >> 4, c = t & 15; hjs[t] = h2[nodes[j] * 16 + c]; }
    for (int t = tid; t < 128; t += 256) g1s[t] = gate1_w[t];
    for (int t = tid; t < 2048; t += 256) e1ws[t] = e1_w[t];
    for (int t = tid; t < 64; t += 256) e1bs[t] = e1_b[t];
    for (int t = tid; t < 64; t += 256) g2s[t] = gate2_w[t];
    for (int t = tid; t < 128; t += 256) e2ws[t] = e2_w[t];
    if (tid < 8) e2bs[tid] = e2_b[tid];
    __syncthreads();

    int m = blockIdx.x * 256 + tid;
    if (m >= M) return;
    int i = m / 50, j = m - i * 50;

    float xs[32];
    int ni = nodes[i];
    float4 a0 = *(const float4*)&h2[ni * 16];
    float4 a1 = *(const float4*)&h2[ni * 16 + 4];
    float4 a2 = *(const float4*)&h2[ni * 16 + 8];
    float4 a3 = *(const float4*)&h2[ni * 16 + 12];
    xs[0]=a0.x; xs[1]=a0.y; xs[2]=a0.z; xs[3]=a0.w;
    xs[4]=a1.x; xs[5]=a1.y; xs[6]=a1.z; xs[7]=a1.w;
    xs[8]=a2.x; xs[9]=a2.y; xs[10]=a2.z; xs[11]=a2.w;
    xs[12]=a3.x; xs[13]=a3.y; xs[14]=a3.z; xs[15]=a3.w;
    #pragma unroll
    for (int c = 0; c < 16; ++c) xs[16 + c] = hjs[j * 16 + c];

    #pragma unroll
    for (int c = 0; c < 32; c += 4)
        *(float4*)&out2[(size_t)m * 32 + c] = make_float4(xs[c], xs[c+1], xs[c+2], xs[c+3]);

    float g[4] = {0.f, 0.f, 0.f, 0.f};
    #pragma unroll
    for (int c = 0; c < 32; ++c) {
        float xv = xs[c];
        #pragma unroll
        for (int e = 0; e < 4; ++e) g[e] += xv * g1s[c * 4 + e];
    }
    int idx = 0; float best = g[0];
    #pragma unroll
    for (int e = 1; e < 4; ++e) if (g[e] > best) { best = g[e]; idx = e; }
    float z[16];
    #pragma unroll
    for (int o = 0; o < 16; ++o) {
        float a = e1bs[idx * 16 + o];
        #pragma unroll
        for (int c = 0; c < 32; ++c) a += xs[c] * e1ws[(idx * 32 + c) * 16 + o];
        z[o] = fmaxf(a, 0.f);
    }

    float g2[4] = {0.f, 0.f, 0.f, 0.f};
    #pragma unroll
    for (int c = 0; c < 16; ++c) {
        float zv = z[c];
        #pragma unroll
        for (int e = 0; e < 4; ++e) g2[e] += zv * g2s[c * 4 + e];
    }
    int idx2 = 0; float best2 = g2[0];
    #pragma unroll
    for (int e = 1; e < 4; ++e) if (g2[e] > best2) { best2 = g2[e]; idx2 = e; }
    float z2[2];
    #pragma unroll
    for (int o = 0; o < 2; ++o) {
        float a = e2bs[idx2 * 2 + o];
        #pragma unroll
        for (int c = 0; c < 16; ++c) a += z[c] * e2ws[(idx2 * 16 + c) * 2 + o];
        z2[o] = a;
    }

    float mx = fmaxf(z2[0], z2[1]);
    float l = logf(expf(z2[0] - mx) + expf(z2[1] - mx));
    out1[(size_t)m * 2 + 0] = z2[0] - mx - l;
    out1[(size_t)m * 2 + 1] = z2[1] - mx - l;
}

extern "C" void kernel_launch(void* const* d_in, const int* in_sizes, int n_in,
                              void* d_out, int out_size, void* d_ws, size_t ws_size,
                              hipStream_t stream) {
    const float* x       = (const float*)d_in[0];
    const float* w1      = (const float*)d_in[1];
    const float* b1      = (const float*)d_in[2];
    const float* w2      = (const float*)d_in[3];
    const float* b2      = (const float*)d_in[4];
    const float* gate1_w = (const float*)d_in[5];
    const float* e1_w    = (const float*)d_in[6];
    const float* e1_b    = (const float*)d_in[7];
    const float* gate2_w = (const float*)d_in[8];
    const float* e2_w    = (const float*)d_in[9];
    const float* e2_b    = (const float*)d_in[10];
    const int*   ei      = (const int*)d_in[11];
    const int*   nodes   = (const int*)d_in[12];

    const int n    = in_sizes[0] / 256;      // 100000
    const int nE   = in_sizes[11] / 2;       // 3200000
    const int nsel = in_sizes[12];           // 4096
    const int M    = nsel * 50;              // 204800
    const int nb   = (n + NPB - 1) / NPB;    // 1563

    size_t off = 0;
    auto alloc = [&](size_t bytes) -> void* {
        void* p = (char*)d_ws + off;
        off += (bytes + 255) & ~(size_t)255;
        return p;
    };
    float*  dis    = (float*)alloc((size_t)n * 4);
    int*    bhist  = (int*)alloc((size_t)nb * 4);
    int*    boffs  = (int*)alloc((size_t)(nb + 1) * 4);
    int*    gcur   = (int*)alloc((size_t)nb * 4);
    int*    noffs  = (int*)alloc((size_t)(n + 1) * 4);
    int*    keys   = (int*)alloc((size_t)nE * 4);   // becomes srcs after nodesort
    __half* hw1h   = (__half*)alloc((size_t)n * 32 * 2);
    float*  hw2s   = (float*)alloc((size_t)n * 16 * 4);
    float*  h2     = (float*)alloc((size_t)n * 16 * 4);
    if (off > ws_size) return;

    float* out1 = (float*)d_out;              // [M,2]
    float* out2 = out1 + (size_t)M * 2;       // [M,32]

    zero_kernel<<<(nb + 255) / 256, 256, 0, stream>>>(bhist, nb);
    histA_kernel<<<(nE + 4095) / 4096, 256, 0, stream>>>(ei, bhist, nE, nb);
    scanB_kernel<<<1, 256, 0, stream>>>(bhist, boffs, gcur, nb);
    scatterC_kernel<<<(nE + BATCH - 1) / BATCH, 256, 0, stream>>>(ei, gcur, keys, nE, nb);
    nodesort_kernel<<<nb, 256, 0, stream>>>(keys, boffs, noffs, dis, n, nb);
    hw1s_kernel<<<768, 256, 0, stream>>>(x, w1, dis, hw1h, n);
    gatherG1_kernel<<<(n + 7) / 8, 256, 0, stream>>>(hw1h, dis, keys, noffs, b1, w2, hw2s, n);
    gatherG2_kernel<<<(nsel + 15) / 16, 256, 0, stream>>>(hw2s, dis, keys, noffs, nodes, b2,
                                                          h2, nsel, n);
    pair_moe_kernel<<<(M + 255) / 256, 256, 0, stream>>>(h2, nodes, gate1_w, e1_w, e1_b,
                                                         gate2_w, e2_w, e2_b, out1, out2, M);
}